// Round 12
// baseline (93.328 us; speedup 1.0000x reference)
//
#include <hip/hip_runtime.h>
#include <math.h>

#define BATCH 256
#define KSNIP 32
#define CH    2048
#define CH4   512
#define NCLSS 20

// ---- ws layout (floats) ----
// pkq: 5 arrays [j][k][b][q]  j=0 dot(meanNA,PB_k) 1 ||PB_k||^2
//                             2 dot(meanNB,PA_k) 3 ||PA_k||^2 4 rowsum(PA_k)
#define PKQF(j,k,b,q) (((((j)*32+(k))*256+(b))<<2)+(q))
#define OFF_SCQ 163840          // [6][256][4]: 0:n2PA 1:n2PB 2:n2NA 3:n2NB 4:dAP 5:dBP
#define SCQF(j,b,q) (OFF_SCQ + ((((j)*256+(b))<<2)+(q)))

__device__ __forceinline__ float dot4(float4 a, float4 b) {
    return a.x*b.x + a.y*b.y + a.z*b.z + a.w*b.w;
}
__device__ __forceinline__ float sum4(float4 a) { return a.x + a.y + a.z + a.w; }
__device__ __forceinline__ float4 add4(float4 a, float4 b) {
    return make_float4(a.x+b.x, a.y+b.y, a.z+b.z, a.w+b.w);
}

// Single streaming kernel. Block (b, q): channels [q*512, q*512+512) of all
// four tensors for video b. 4 waves; wave w owns rows k = w + 4*kk.
// Phase N: NA/NB quarter-means -> LDS (never global). Phase P: per-k partials.
__global__ __launch_bounds__(256) void stream_kernel(
    const float* __restrict__ PA, const float* __restrict__ PB,
    const float* __restrict__ NAp, const float* __restrict__ NBp,
    float* __restrict__ ws)
{
    const int b   = blockIdx.x >> 2;
    const int q   = blockIdx.x & 3;
    const int tid = threadIdx.x;
    const int w   = tid >> 6;
    const int l   = tid & 63;
    const int qb  = q * 128;            // float4 base within a row

    const size_t base = (size_t)b * KSNIP * CH;
    const float4* A4  = (const float4*)(NAp + base);
    const float4* B4  = (const float4*)(NBp + base);
    const float4* Pa4 = (const float4*)(PA  + base);
    const float4* Pb4 = (const float4*)(PB  + base);

    __shared__ float4 sNA[128], sNB[128], sPA[128], sPB[128];
    __shared__ float  sW[4][4];

    // ---- phase N: stream NA/NB quarters, column sums ----
    float4 csA0 = {0,0,0,0}, csA1 = {0,0,0,0};
    float4 csB0 = {0,0,0,0}, csB1 = {0,0,0,0};
    {
        float4 va[2][2], vb[2][2];
        va[0][0] = A4[w*CH4 + qb + l];  va[0][1] = A4[w*CH4 + qb + l + 64];
        vb[0][0] = B4[w*CH4 + qb + l];  vb[0][1] = B4[w*CH4 + qb + l + 64];
        #pragma unroll
        for (int kk = 0; kk < 8; ++kk) {
            if (kk < 7) {
                const int kn = w + (kk+1)*4;
                const int cu = (kk+1)&1;
                va[cu][0] = A4[kn*CH4 + qb + l];  va[cu][1] = A4[kn*CH4 + qb + l + 64];
                vb[cu][0] = B4[kn*CH4 + qb + l];  vb[cu][1] = B4[kn*CH4 + qb + l + 64];
            }
            const int c = kk&1;
            csA0 = add4(csA0, va[c][0]); csA1 = add4(csA1, va[c][1]);
            csB0 = add4(csB0, vb[c][0]); csB1 = add4(csB1, vb[c][1]);
        }
    }
    #pragma unroll
    for (int p = 0; p < 4; ++p) {
        if (w == p) {
            if (p == 0) {
                sNA[l] = csA0; sNA[l+64] = csA1;
                sNB[l] = csB0; sNB[l+64] = csB1;
            } else {
                sNA[l] = add4(sNA[l], csA0); sNA[l+64] = add4(sNA[l+64], csA1);
                sNB[l] = add4(sNB[l], csB0); sNB[l+64] = add4(sNB[l+64], csB1);
            }
        }
        __syncthreads();
    }

    // scale to means (in LDS), n2 partials
    float n2a = 0.f, n2b = 0.f;
    if (tid < 128) {
        const float s = 1.0f/32.0f;
        float4 ma = sNA[tid]; ma.x*=s; ma.y*=s; ma.z*=s; ma.w*=s;
        float4 mb = sNB[tid]; mb.x*=s; mb.y*=s; mb.z*=s; mb.w*=s;
        sNA[tid] = ma; sNB[tid] = mb;
        n2a = dot4(ma, ma); n2b = dot4(mb, mb);
    }
    __syncthreads();
    #pragma unroll
    for (int o = 32; o; o >>= 1) {
        n2a += __shfl_xor(n2a, o);
        n2b += __shfl_xor(n2b, o);
    }
    if (l == 0) { sW[w][0] = n2a; sW[w][1] = n2b; }
    __syncthreads();
    if (tid == 0) {
        ws[SCQF(2,b,q)] = sW[0][0]+sW[1][0]+sW[2][0]+sW[3][0];
        ws[SCQF(3,b,q)] = sW[0][1]+sW[1][1]+sW[2][1]+sW[3][1];
    }

    // loop-invariant mean slices for this lane
    const float4 mdA0 = sNA[l], mdA1 = sNA[l+64];
    const float4 mdB0 = sNB[l], mdB1 = sNB[l+64];

    // ---- phase P: stream PA/PB quarters ----
    float4 csP0 = {0,0,0,0}, csP1 = {0,0,0,0};
    float4 csQ0 = {0,0,0,0}, csQ1 = {0,0,0,0};
    float dqA[8], sqA[8], rsA[8], dqB[8], sqB[8];
    {
        float4 va[2][2], vb[2][2];
        va[0][0] = Pa4[w*CH4 + qb + l];  va[0][1] = Pa4[w*CH4 + qb + l + 64];
        vb[0][0] = Pb4[w*CH4 + qb + l];  vb[0][1] = Pb4[w*CH4 + qb + l + 64];
        #pragma unroll
        for (int kk = 0; kk < 8; ++kk) {
            if (kk < 7) {
                const int kn = w + (kk+1)*4;
                const int cu = (kk+1)&1;
                va[cu][0] = Pa4[kn*CH4 + qb + l];  va[cu][1] = Pa4[kn*CH4 + qb + l + 64];
                vb[cu][0] = Pb4[kn*CH4 + qb + l];  vb[cu][1] = Pb4[kn*CH4 + qb + l + 64];
            }
            const int c = kk&1;
            const float4 a0 = va[c][0], a1 = va[c][1];
            const float4 b0 = vb[c][0], b1 = vb[c][1];
            csP0 = add4(csP0, a0); csP1 = add4(csP1, a1);
            csQ0 = add4(csQ0, b0); csQ1 = add4(csQ1, b1);
            dqA[kk] = dot4(mdB0, a0) + dot4(mdB1, a1);
            sqA[kk] = dot4(a0, a0)   + dot4(a1, a1);
            rsA[kk] = sum4(a0)       + sum4(a1);
            dqB[kk] = dot4(mdA0, b0) + dot4(mdA1, b1);
            sqB[kk] = dot4(b0, b0)   + dot4(b1, b1);
        }
    }

    // deferred per-k butterflies; wave owns whole quarter-row -> direct store
    #pragma unroll
    for (int kk = 0; kk < 8; ++kk) {
        #pragma unroll
        for (int o = 32; o; o >>= 1) {
            dqA[kk] += __shfl_xor(dqA[kk], o);
            sqA[kk] += __shfl_xor(sqA[kk], o);
            rsA[kk] += __shfl_xor(rsA[kk], o);
            dqB[kk] += __shfl_xor(dqB[kk], o);
            sqB[kk] += __shfl_xor(sqB[kk], o);
        }
        if (l == 0) {
            const int k = w + kk*4;
            ws[PKQF(0,k,b,q)] = dqB[kk];
            ws[PKQF(1,k,b,q)] = sqB[kk];
            ws[PKQF(2,k,b,q)] = dqA[kk];
            ws[PKQF(3,k,b,q)] = sqA[kk];
            ws[PKQF(4,k,b,q)] = rsA[kk];
        }
    }

    // colsum combine for P -> quarter means -> n2P/dAP/dBP partials
    #pragma unroll
    for (int p = 0; p < 4; ++p) {
        if (w == p) {
            if (p == 0) {
                sPA[l] = csP0; sPA[l+64] = csP1;
                sPB[l] = csQ0; sPB[l+64] = csQ1;
            } else {
                sPA[l] = add4(sPA[l], csP0); sPA[l+64] = add4(sPA[l+64], csP1);
                sPB[l] = add4(sPB[l], csQ0); sPB[l+64] = add4(sPB[l+64], csQ1);
            }
        }
        __syncthreads();
    }

    float n2pa = 0.f, n2pb = 0.f, dap = 0.f, dbp = 0.f;
    if (tid < 128) {
        const float s = 1.0f/32.0f;
        float4 mpa = sPA[tid]; mpa.x*=s; mpa.y*=s; mpa.z*=s; mpa.w*=s;
        float4 mpb = sPB[tid]; mpb.x*=s; mpb.y*=s; mpb.z*=s; mpb.w*=s;
        n2pa = dot4(mpa, mpa);
        n2pb = dot4(mpb, mpb);
        dap  = dot4(sNA[tid], mpa);
        dbp  = dot4(sNB[tid], mpb);
    }
    #pragma unroll
    for (int o = 32; o; o >>= 1) {
        n2pa += __shfl_xor(n2pa, o);
        n2pb += __shfl_xor(n2pb, o);
        dap  += __shfl_xor(dap, o);
        dbp  += __shfl_xor(dbp, o);
    }
    __syncthreads();
    if (l == 0) { sW[w][0] = n2pa; sW[w][1] = n2pb; sW[w][2] = dap; sW[w][3] = dbp; }
    __syncthreads();
    if (tid == 0) {
        ws[SCQF(0,b,q)] = sW[0][0]+sW[1][0]+sW[2][0]+sW[3][0];
        ws[SCQF(1,b,q)] = sW[0][1]+sW[1][1]+sW[2][1]+sW[3][1];
        ws[SCQF(4,b,q)] = sW[0][2]+sW[1][2]+sW[2][2]+sW[3][2];
        ws[SCQF(5,b,q)] = sW[0][3]+sW[1][3]+sW[2][3]+sW[3][3];
    }
}

// finish: single block, 256 threads (thread == video b).
__global__ __launch_bounds__(256) void finish_kernel(
    const float* __restrict__ vs, const float* __restrict__ label,
    const float* __restrict__ ws, float* __restrict__ out)
{
    const int tid  = threadIdx.x;
    const int b    = tid;
    const int lane = tid & 63;
    const int w    = tid >> 6;

    __shared__ float sLab[NCLSS*BATCH];           // [c][b]
    __shared__ float sVS [NCLSS*BATCH];           // [c][b]
    __shared__ float an[BATCH][33];
    __shared__ float sD[NCLSS][BATCH];
    __shared__ unsigned long long sMask[NCLSS][4];
    __shared__ int   sAnchor[NCLSS];
    __shared__ int   sCnt[NCLSS];
    __shared__ float sbuf[4];
    __shared__ float stp[4];

    const float4* pkq = (const float4*)ws;                 // [(j*32+k)*256 + b]
    const float4* sc4 = (const float4*)(ws + OFF_SCQ);     // [j*256 + b]
    #define PK4(j,k) (((j)*32+(k))*256)

    #pragma unroll
    for (int j = 0; j < NCLSS; ++j) {
        const int i = j*BATCH + tid;
        const int c = i % NCLSS;
        const int bb = i / NCLSS;
        sLab[c*BATCH + bb] = label[i];
        sVS [c*BATCH + bb] = vs[i];
    }
    #pragma unroll
    for (int j = 0; j < KSNIP; ++j) {
        const int i = j*BATCH + tid;       // k=i>>8, b=i&255
        an[i & 255][i >> 8] = sum4(pkq[PK4(4, i >> 8) + (i & 255)]);
    }
    __syncthreads();

    {
        float nrm = 0.f;
        #pragma unroll
        for (int k = 0; k < KSNIP; ++k) { float v = an[b][k]; nrm += v*v; }
        const float inv = 1.0f / sqrtf(nrm);
        #pragma unroll
        for (int k = 0; k < KSNIP; ++k) an[b][k] *= inv;
    }

    const float invT = 1.0f / 0.07f;
    const float nPA = sqrtf(sum4(sc4[0*256 + b]));
    const float nPB = sqrtf(sum4(sc4[1*256 + b]));
    const float nNA = sqrtf(sum4(sc4[2*256 + b]));
    const float nNB = sqrtf(sum4(sc4[3*256 + b]));
    const float dAP = sum4(sc4[4*256 + b]);
    const float dBP = sum4(sc4[5*256 + b]);

    float nce;
    {   // NCE 1: q=meanNA, neg=PB
        const float lpos = dAP / (nNA * nPA) * invT;
        float vv[KSNIP];
        #pragma unroll
        for (int k = 0; k < KSNIP; ++k) {
            const float dq = sum4(pkq[PK4(0,k) + b]);
            const float sq = sum4(pkq[PK4(1,k) + b]);
            vv[k] = dq * invT / (nNA * sqrtf(sq));
        }
        float m = lpos;
        #pragma unroll
        for (int k = 0; k < KSNIP; ++k) m = fmaxf(m, vv[k]);
        float s = expf(lpos - m);
        #pragma unroll
        for (int k = 0; k < KSNIP; ++k) s += expf(vv[k] - m);
        nce = logf(s) + m - lpos;
    }
    {   // NCE 2: q=meanNB, neg=PA
        const float lpos = dBP / (nNB * nPB) * invT;
        float vv[KSNIP];
        #pragma unroll
        for (int k = 0; k < KSNIP; ++k) {
            const float dq = sum4(pkq[PK4(2,k) + b]);
            const float sq = sum4(pkq[PK4(3,k) + b]);
            vv[k] = dq * invT / (nNB * sqrtf(sq));
        }
        float m = lpos;
        #pragma unroll
        for (int k = 0; k < KSNIP; ++k) m = fmaxf(m, vv[k]);
        float s = expf(lpos - m);
        #pragma unroll
        for (int k = 0; k < KSNIP; ++k) s += expf(vv[k] - m);
        nce += logf(s) + m - lpos;
    }

    const float la   = fmaxf(150.0f - nPA, 0.0f);
    const float absb = (la + nPB) * (la + nPB);

    float rs = 0.0f;
    #pragma unroll
    for (int c = 0; c < NCLSS; ++c) rs += sLab[c*BATCH + b];
    float clsb = 0.0f;
    #pragma unroll
    for (int c = 0; c < NCLSS; ++c) {
        const float l = sLab[c*BATCH + b] / rs;
        const float p = sVS [c*BATCH + b];
        clsb -= l * logf(p) + (1.0f - l) * logf(1.0f - p);
    }

    auto blocksum = [&](float v) -> float {
        #pragma unroll
        for (int o = 32; o; o >>= 1) v += __shfl_xor(v, o);
        __syncthreads();
        if (lane == 0) sbuf[w] = v;
        __syncthreads();
        return sbuf[0] + sbuf[1] + sbuf[2] + sbuf[3];
    };

    const float loss_snico = blocksum(nce)  / 256.0f;
    const float loss_abs   = blocksum(absb) / 256.0f;
    const float loss_cls   = blocksum(clsb) / 5120.0f;

    #pragma unroll
    for (int c = 0; c < NCLSS; ++c) {
        const bool mm = sLab[c*BATCH + b] > 0.5f;
        const unsigned long long mk = __ballot(mm);
        if (lane == 0) sMask[c][w] = mk;
    }
    __syncthreads();
    if (tid < NCLSS) {
        int cnt = 0, anchor = -1;
        #pragma unroll
        for (int qq = 3; qq >= 0; --qq) {
            const unsigned long long mq = sMask[tid][qq];
            cnt += __builtin_popcountll(mq);
            if (anchor < 0 && mq) anchor = qq*64 + 63 - __builtin_clzll(mq);
        }
        sAnchor[tid] = anchor;
        sCnt[tid]    = cnt;
    }
    __syncthreads();

    #pragma unroll
    for (int c = 0; c < NCLSS; ++c) {
        if (sCnt[c] > 1) {
            const int a = sAnchor[c];
            float acc = 0.f;
            #pragma unroll
            for (int k = 0; k < KSNIP; ++k) acc += an[a][k] * an[b][k];
            sD[c][b] = 1.0f - acc;
        }
    }
    __syncthreads();

    float tripw = 0.f;
    #pragma unroll
    for (int cc = 0; cc < 5; ++cc) {
        const int c = w*5 + cc;
        if (sCnt[c] > 1) {
            const int a = sAnchor[c];
            float vAll = -__builtin_inff();
            float vMem = -__builtin_inff();
            float vNon =  __builtin_inff();
            #pragma unroll
            for (int qq = 0; qq < 4; ++qq) {
                const int bb = lane + qq*64;
                const float d = sD[c][bb];
                const bool mm = (sMask[c][qq] >> lane) & 1ull;
                vAll = fmaxf(vAll, d);
                if (mm && bb != a) vMem = fmaxf(vMem, d);
                if (!mm)           vNon = fminf(vNon, d);
            }
            #pragma unroll
            for (int o = 32; o; o >>= 1) {
                vAll = fmaxf(vAll, __shfl_xor(vAll, o));
                vMem = fmaxf(vMem, __shfl_xor(vMem, o));
                vNon = fminf(vNon, __shfl_xor(vNon, o));
            }
            if (lane == 0) {
                const float max_d = fmaxf(0.0f, vMem);
                const float min_d = fminf(vAll, vNon);
                tripw += fmaxf(max_d - min_d + 0.8f, 0.0f);
            }
        }
    }
    if (lane == 0) stp[w] = tripw;
    __syncthreads();

    if (tid == 0) {
        const float trip_total = stp[0] + stp[1] + stp[2] + stp[3];
        const float total = loss_cls + 0.01f * loss_snico + 0.0005f * loss_abs + 0.005f * trip_total;
        out[0] = total;
        out[1] = loss_cls;
        out[2] = loss_snico;
        out[3] = loss_abs;
        out[4] = trip_total;
    }
}

extern "C" void kernel_launch(void* const* d_in, const int* in_sizes, int n_in,
                              void* d_out, int out_size, void* d_ws, size_t ws_size,
                              hipStream_t stream) {
    const float* vs    = (const float*)d_in[0];
    const float* label = (const float*)d_in[1];
    const float* PA    = (const float*)d_in[2];
    const float* PB    = (const float*)d_in[3];
    const float* NAp   = (const float*)d_in[4];
    const float* NBp   = (const float*)d_in[5];
    float* ws  = (float*)d_ws;
    float* out = (float*)d_out;

    stream_kernel<<<dim3(4*BATCH), dim3(256), 0, stream>>>(PA, PB, NAp, NBp, ws);
    finish_kernel<<<dim3(1),       dim3(256), 0, stream>>>(vs, label, ws, out);
}

// Round 13
// 83.807 us; speedup vs baseline: 1.1136x; 1.1136x over previous
//
#include <hip/hip_runtime.h>
#include <math.h>

#define BATCH 256
#define KSNIP 32
#define CH    2048
#define CH4   512
#define NCLSS 20

// ---- ws layout (floats) ----
#define OFF_MNA 0               // [256][2048] meanNA
#define OFF_MNB 524288          // [256][2048] meanNB
#define OFF_PK  1048576         // 5 arrays, K-MAJOR [k*256+b]:
                                // j=0 dot(meanNA,PB_k)  j=1 ||PB_k||^2
                                // j=2 dot(meanNB,PA_k)  j=3 ||PA_k||^2
                                // j=4 rowsum(PA_k)
#define PKN 8192
#define OFF_SC  1089536         // 0:n2PA 1:n2PB 2:n2NA 3:n2NB 4:dAP 5:dBP (each [256])

__device__ __forceinline__ float dot4(float4 a, float4 b) {
    return a.x*b.x + a.y*b.y + a.z*b.z + a.w*b.w;
}
__device__ __forceinline__ float sum4(float4 a) { return a.x + a.y + a.z + a.w; }
__device__ __forceinline__ float4 add4(float4 a, float4 b) {
    return make_float4(a.x+b.x, a.y+b.y, a.z+b.z, a.w+b.w);
}

// K1: block (t,b), t=0:NA t=1:NB. Wave pair shares a row; 2-deep prefetch.
// (best-measured configuration: 84.2us total)
__global__ __launch_bounds__(512) void meanNK_kernel(
    const float* __restrict__ NAp, const float* __restrict__ NBp,
    float* __restrict__ ws)
{
    const int t   = blockIdx.x >> 8;
    const int b   = blockIdx.x & 255;
    const int tid = threadIdx.x;
    const int w   = tid >> 6;
    const int l   = tid & 63;
    const int ch  = (w & 1)*256 + l;    // float4 base index within a row
    const int kr  = w >> 1;             // starting row

    const float4* src = (const float4*)((t ? NBp : NAp) + (size_t)b * KSNIP * CH);

    float4 cs[4];
    #pragma unroll
    for (int j = 0; j < 4; ++j) cs[j] = make_float4(0.f,0.f,0.f,0.f);

    float4 v[2][4];
    #pragma unroll
    for (int j = 0; j < 4; ++j) v[0][j] = src[kr*CH4 + ch + j*64];

    #pragma unroll
    for (int kk = 0; kk < 8; ++kk) {
        if (kk < 7) {
            const int kn = kr + (kk+1)*4;
            #pragma unroll
            for (int j = 0; j < 4; ++j) v[(kk+1)&1][j] = src[kn*CH4 + ch + j*64];
        }
        #pragma unroll
        for (int j = 0; j < 4; ++j) cs[j] = add4(cs[j], v[kk&1][j]);
    }

    __shared__ float4 sCol[CH4];
    __shared__ float  sW[8];
    #pragma unroll
    for (int p = 0; p < 4; ++p) {
        if ((w >> 1) == p) {
            #pragma unroll
            for (int j = 0; j < 4; ++j) {
                const int c = ch + j*64;
                sCol[c] = (p == 0) ? cs[j] : add4(sCol[c], cs[j]);
            }
        }
        __syncthreads();
    }

    float4 m = sCol[tid];
    const float s = 1.0f/32.0f;
    m.x *= s; m.y *= s; m.z *= s; m.w *= s;
    ((float4*)(ws + (t ? OFF_MNB : OFF_MNA) + b*CH))[tid] = m;

    float v2 = dot4(m, m);
    #pragma unroll
    for (int o = 32; o; o >>= 1) v2 += __shfl_xor(v2, o);
    if (l == 0) sW[w] = v2;
    __syncthreads();
    if (tid == 0) {
        float tot = 0.f;
        #pragma unroll
        for (int i = 0; i < 8; ++i) tot += sW[i];
        ws[OFF_SC + (2 + t)*256 + b] = tot;   // 2:n2NA 3:n2NB
    }
}

// K2: block (t,b). 3-deep prefetch + float2-packed consume (SLP -> v_pk ops).
__global__ __launch_bounds__(512) void dots_kernel(
    const float* __restrict__ PA, const float* __restrict__ PB,
    float* __restrict__ ws)
{
    const int t   = blockIdx.x >> 8;
    const int b   = blockIdx.x & 255;
    const int tid = threadIdx.x;
    const int w   = tid >> 6;
    const int l   = tid & 63;
    const int ch  = (w & 1)*256 + l;
    const int kr  = w >> 1;

    const float4* src  = (const float4*)((t ? PB : PA) + (size_t)b * KSNIP * CH);
    const float4* mDot = (const float4*)(ws + (t ? OFF_MNA : OFF_MNB) + b*CH);
    const float4* mDap = (const float4*)(ws + (t ? OFF_MNB : OFF_MNA) + b*CH);

    float4 md[4];
    #pragma unroll
    for (int j = 0; j < 4; ++j) md[j] = mDot[ch + j*64];

    float4 cs[4];
    #pragma unroll
    for (int j = 0; j < 4; ++j) cs[j] = make_float4(0.f,0.f,0.f,0.f);

    float dqA[8], sqA[8], rsA[8];

    float4 v[3][4];
    #pragma unroll
    for (int p = 0; p < 2; ++p) {
        #pragma unroll
        for (int j = 0; j < 4; ++j) v[p][j] = src[(kr + p*4)*CH4 + ch + j*64];
    }

    #pragma unroll
    for (int kk = 0; kk < 8; ++kk) {
        if (kk < 6) {
            const int kn = kr + (kk+2)*4;
            #pragma unroll
            for (int j = 0; j < 4; ++j) v[(kk+2)%3][j] = src[kn*CH4 + ch + j*64];
        }
        float2 dq2 = make_float2(0.f,0.f);
        float2 sq2 = make_float2(0.f,0.f);
        float2 rs2 = make_float2(0.f,0.f);
        #pragma unroll
        for (int j = 0; j < 4; ++j) {
            const float4 a = v[kk%3][j];
            // pairwise (x,y)/(z,w) ops -> v_pk_add / v_pk_fma candidates
            cs[j].x += a.x; cs[j].y += a.y;
            cs[j].z += a.z; cs[j].w += a.w;
            dq2.x += md[j].x*a.x; dq2.y += md[j].y*a.y;
            dq2.x += md[j].z*a.z; dq2.y += md[j].w*a.w;
            sq2.x += a.x*a.x;     sq2.y += a.y*a.y;
            sq2.x += a.z*a.z;     sq2.y += a.w*a.w;
            rs2.x += a.x;         rs2.y += a.y;
            rs2.x += a.z;         rs2.y += a.w;
        }
        dqA[kk] = dq2.x + dq2.y;
        sqA[kk] = sq2.x + sq2.y;
        rsA[kk] = rs2.x + rs2.y;
    }

    // deferred per-k butterflies -> per-wave halves in sPar
    __shared__ float sPar[8][8][3];
    #pragma unroll
    for (int kk = 0; kk < 8; ++kk) {
        #pragma unroll
        for (int o = 32; o; o >>= 1) {
            dqA[kk] += __shfl_xor(dqA[kk], o);
            sqA[kk] += __shfl_xor(sqA[kk], o);
            rsA[kk] += __shfl_xor(rsA[kk], o);
        }
        if (l == 0) {
            sPar[w][kk][0] = dqA[kk];
            sPar[w][kk][1] = sqA[kk];
            sPar[w][kk][2] = rsA[kk];
        }
    }
    __syncthreads();

    // combine wave-pair halves, write per-k results (k = (w>>1)+4*kk)
    if (tid < KSNIP) {
        const int k  = tid;
        const int wp = 2*(k & 3);
        const int kk = k >> 2;
        const float dq = sPar[wp][kk][0] + sPar[wp+1][kk][0];
        const float sq = sPar[wp][kk][1] + sPar[wp+1][kk][1];
        const float rs = sPar[wp][kk][2] + sPar[wp+1][kk][2];
        const int idx = k*BATCH + b;   // K-MAJOR
        if (t == 0) {   // PA
            ws[OFF_PK + 2*PKN + idx] = dq;
            ws[OFF_PK + 3*PKN + idx] = sq;
            ws[OFF_PK + 4*PKN + idx] = rs;
        } else {        // PB
            ws[OFF_PK + 0*PKN + idx] = dq;
            ws[OFF_PK + 1*PKN + idx] = sq;
        }
    }

    // colsum combine -> meanP -> n2, dap
    __shared__ float4 sCol[CH4];
    __shared__ float  sW[8][2];
    #pragma unroll
    for (int p = 0; p < 4; ++p) {
        if ((w >> 1) == p) {
            #pragma unroll
            for (int j = 0; j < 4; ++j) {
                const int c = ch + j*64;
                sCol[c] = (p == 0) ? cs[j] : add4(sCol[c], cs[j]);
            }
        }
        __syncthreads();
    }

    float4 m = sCol[tid];
    const float s = 1.0f/32.0f;
    m.x *= s; m.y *= s; m.z *= s; m.w *= s;
    float n2  = dot4(m, m);
    float dap = dot4(mDap[tid], m);
    #pragma unroll
    for (int o = 32; o; o >>= 1) {
        n2  += __shfl_xor(n2, o);
        dap += __shfl_xor(dap, o);
    }
    if (l == 0) { sW[w][0] = n2; sW[w][1] = dap; }
    __syncthreads();
    if (tid == 0) {
        float t0 = 0.f, t1 = 0.f;
        #pragma unroll
        for (int i = 0; i < 8; ++i) { t0 += sW[i][0]; t1 += sW[i][1]; }
        ws[OFF_SC + t*256 + b]       = t0;   // 0:n2PA 1:n2PB
        ws[OFF_SC + (4 + t)*256 + b] = t1;   // 4:dAP  5:dBP
    }
}

// K3: single block, 256 threads (thread == video b). Latency-optimized finish.
__global__ __launch_bounds__(256) void finish_kernel(
    const float* __restrict__ vs, const float* __restrict__ label,
    const float* __restrict__ ws, float* __restrict__ out)
{
    const int tid  = threadIdx.x;
    const int b    = tid;
    const int lane = tid & 63;
    const int w    = tid >> 6;

    __shared__ float sLab[NCLSS*BATCH];           // [c][b]
    __shared__ float sVS [NCLSS*BATCH];           // [c][b]
    __shared__ float an[BATCH][33];
    __shared__ float sD[NCLSS][BATCH];
    __shared__ unsigned long long sMask[NCLSS][4];
    __shared__ int   sAnchor[NCLSS];
    __shared__ int   sCnt[NCLSS];
    __shared__ float sbuf[4];
    __shared__ float stp[4];

    const float* pk = ws + OFF_PK;

    #pragma unroll
    for (int j = 0; j < NCLSS; ++j) {
        const int i = j*BATCH + tid;
        const int c = i % NCLSS;
        const int bb = i / NCLSS;
        sLab[c*BATCH + bb] = label[i];
        sVS [c*BATCH + bb] = vs[i];
    }
    #pragma unroll
    for (int j = 0; j < KSNIP; ++j) {
        const int i = j*BATCH + tid;       // k-major: k=i>>8, b=i&255
        an[i & 255][i >> 8] = pk[4*PKN + i];
    }
    __syncthreads();

    {
        float nrm = 0.f;
        #pragma unroll
        for (int k = 0; k < KSNIP; ++k) { float v = an[b][k]; nrm += v*v; }
        const float inv = 1.0f / sqrtf(nrm);
        #pragma unroll
        for (int k = 0; k < KSNIP; ++k) an[b][k] *= inv;
    }

    const float invT = 1.0f / 0.07f;
    const float nPA = sqrtf(ws[OFF_SC + 0*256 + b]);
    const float nPB = sqrtf(ws[OFF_SC + 1*256 + b]);
    const float nNA = sqrtf(ws[OFF_SC + 2*256 + b]);
    const float nNB = sqrtf(ws[OFF_SC + 3*256 + b]);
    const float dAP = ws[OFF_SC + 4*256 + b];
    const float dBP = ws[OFF_SC + 5*256 + b];

    float nce;
    {   // NCE 1: q=meanNA, neg=PB
        const float lpos = dAP / (nNA * nPA) * invT;
        float vv[KSNIP];
        #pragma unroll
        for (int k = 0; k < KSNIP; ++k) {
            const float dq = pk[0*PKN + k*BATCH + b];
            const float sq = pk[1*PKN + k*BATCH + b];
            vv[k] = dq * invT / (nNA * sqrtf(sq));
        }
        float m = lpos;
        #pragma unroll
        for (int k = 0; k < KSNIP; ++k) m = fmaxf(m, vv[k]);
        float s = expf(lpos - m);
        #pragma unroll
        for (int k = 0; k < KSNIP; ++k) s += expf(vv[k] - m);
        nce = logf(s) + m - lpos;
    }
    {   // NCE 2: q=meanNB, neg=PA
        const float lpos = dBP / (nNB * nPB) * invT;
        float vv[KSNIP];
        #pragma unroll
        for (int k = 0; k < KSNIP; ++k) {
            const float dq = pk[2*PKN + k*BATCH + b];
            const float sq = pk[3*PKN + k*BATCH + b];
            vv[k] = dq * invT / (nNB * sqrtf(sq));
        }
        float m = lpos;
        #pragma unroll
        for (int k = 0; k < KSNIP; ++k) m = fmaxf(m, vv[k]);
        float s = expf(lpos - m);
        #pragma unroll
        for (int k = 0; k < KSNIP; ++k) s += expf(vv[k] - m);
        nce += logf(s) + m - lpos;
    }

    const float la   = fmaxf(150.0f - nPA, 0.0f);
    const float absb = (la + nPB) * (la + nPB);

    float rs = 0.0f;
    #pragma unroll
    for (int c = 0; c < NCLSS; ++c) rs += sLab[c*BATCH + b];
    float clsb = 0.0f;
    #pragma unroll
    for (int c = 0; c < NCLSS; ++c) {
        const float l = sLab[c*BATCH + b] / rs;
        const float p = sVS [c*BATCH + b];
        clsb -= l * logf(p) + (1.0f - l) * logf(1.0f - p);
    }

    auto blocksum = [&](float v) -> float {
        #pragma unroll
        for (int o = 32; o; o >>= 1) v += __shfl_xor(v, o);
        __syncthreads();
        if (lane == 0) sbuf[w] = v;
        __syncthreads();
        return sbuf[0] + sbuf[1] + sbuf[2] + sbuf[3];
    };

    const float loss_snico = blocksum(nce)  / 256.0f;
    const float loss_abs   = blocksum(absb) / 256.0f;
    const float loss_cls   = blocksum(clsb) / 5120.0f;

    #pragma unroll
    for (int c = 0; c < NCLSS; ++c) {
        const bool mm = sLab[c*BATCH + b] > 0.5f;
        const unsigned long long mk = __ballot(mm);
        if (lane == 0) sMask[c][w] = mk;
    }
    __syncthreads();
    if (tid < NCLSS) {
        int cnt = 0, anchor = -1;
        #pragma unroll
        for (int q = 3; q >= 0; --q) {
            const unsigned long long mq = sMask[tid][q];
            cnt += __builtin_popcountll(mq);
            if (anchor < 0 && mq) anchor = q*64 + 63 - __builtin_clzll(mq);
        }
        sAnchor[tid] = anchor;
        sCnt[tid]    = cnt;
    }
    __syncthreads();

    #pragma unroll
    for (int c = 0; c < NCLSS; ++c) {
        if (sCnt[c] > 1) {
            const int a = sAnchor[c];
            float acc = 0.f;
            #pragma unroll
            for (int k = 0; k < KSNIP; ++k) acc += an[a][k] * an[b][k];
            sD[c][b] = 1.0f - acc;
        }
    }
    __syncthreads();

    float tripw = 0.f;
    #pragma unroll
    for (int cc = 0; cc < 5; ++cc) {
        const int c = w*5 + cc;
        if (sCnt[c] > 1) {
            const int a = sAnchor[c];
            float vAll = -__builtin_inff();
            float vMem = -__builtin_inff();
            float vNon =  __builtin_inff();
            #pragma unroll
            for (int q = 0; q < 4; ++q) {
                const int bb = lane + q*64;
                const float d = sD[c][bb];
                const bool mm = (sMask[c][q] >> lane) & 1ull;
                vAll = fmaxf(vAll, d);
                if (mm && bb != a) vMem = fmaxf(vMem, d);
                if (!mm)           vNon = fminf(vNon, d);
            }
            #pragma unroll
            for (int o = 32; o; o >>= 1) {
                vAll = fmaxf(vAll, __shfl_xor(vAll, o));
                vMem = fmaxf(vMem, __shfl_xor(vMem, o));
                vNon = fminf(vNon, __shfl_xor(vNon, o));
            }
            if (lane == 0) {
                const float max_d = fmaxf(0.0f, vMem);
                const float min_d = fminf(vAll, vNon);
                tripw += fmaxf(max_d - min_d + 0.8f, 0.0f);
            }
        }
    }
    if (lane == 0) stp[w] = tripw;
    __syncthreads();

    if (tid == 0) {
        const float trip_total = stp[0] + stp[1] + stp[2] + stp[3];
        const float total = loss_cls + 0.01f * loss_snico + 0.0005f * loss_abs + 0.005f * trip_total;
        out[0] = total;
        out[1] = loss_cls;
        out[2] = loss_snico;
        out[3] = loss_abs;
        out[4] = trip_total;
    }
}

extern "C" void kernel_launch(void* const* d_in, const int* in_sizes, int n_in,
                              void* d_out, int out_size, void* d_ws, size_t ws_size,
                              hipStream_t stream) {
    const float* vs    = (const float*)d_in[0];
    const float* label = (const float*)d_in[1];
    const float* PA    = (const float*)d_in[2];
    const float* PB    = (const float*)d_in[3];
    const float* NAp   = (const float*)d_in[4];
    const float* NBp   = (const float*)d_in[5];
    float* ws  = (float*)d_ws;
    float* out = (float*)d_out;

    meanNK_kernel<<<dim3(512), dim3(512), 0, stream>>>(NAp, NBp, ws);
    dots_kernel  <<<dim3(512), dim3(512), 0, stream>>>(PA, PB, ws);
    finish_kernel<<<dim3(1),   dim3(256), 0, stream>>>(vs, label, ws, out);
}